// Round 12
// baseline (273.607 us; speedup 1.0000x reference)
//
#include <hip/hip_runtime.h>
#include <hip/hip_bf16.h>

#define NEG_SLOPE 0.01f
#define NBUK_MAX 256
#define ATILE 2048

typedef __attribute__((ext_vector_type(8))) short short8;
typedef __attribute__((ext_vector_type(4))) float f32x4;

__device__ __forceinline__ float lrelu(float x) { return x > 0.f ? x : NEG_SLOPE * x; }

// f32 -> bf16 bits, round-to-nearest-even
__device__ __forceinline__ unsigned short f2bf(float f) {
    unsigned u = __builtin_bit_cast(unsigned, f);
    u += 0x7fffu + ((u >> 16) & 1u);
    return (unsigned short)(u >> 16);
}
__device__ __forceinline__ float bf2f(unsigned short h) {
    return __builtin_bit_cast(float, (unsigned)h << 16);
}
__device__ __forceinline__ float bflo(unsigned u) {
    return __builtin_bit_cast(float, u << 16);
}
__device__ __forceinline__ float bfhi(unsigned u) {
    return __builtin_bit_cast(float, u & 0xffff0000u);
}

// Fused prep: feat16 = bf16(features); rmap; bucket_count histogram of dst>>8;
// transposed bf16 weights. (histA fused in: one fewer launch.)
__global__ __launch_bounds__(256) void prep_kernel(
        const float* __restrict__ features, const int* __restrict__ batch,
        const int* __restrict__ root_idx, const float* __restrict__ W1,
        const float* __restrict__ W2, const float* __restrict__ Wl,
        const int* __restrict__ dst, unsigned short* __restrict__ feat16,
        int* __restrict__ rmap, int* __restrict__ bucket_count,
        unsigned short* __restrict__ wt1, unsigned short* __restrict__ wt2,
        unsigned short* __restrict__ wtl, int N, int E, int nbuk) {
    __shared__ int hist[NBUK_MAX];
    if (threadIdx.x < nbuk) hist[threadIdx.x] = 0;
    __syncthreads();
    const int total = N * 32;  // float4 groups of features (N*32 > E here)
    for (int i = blockIdx.x * blockDim.x + threadIdx.x; i < total;
         i += gridDim.x * blockDim.x) {
        float4 v = *(const float4*)(features + (size_t)i * 4);
        ushort4 p;
        p.x = f2bf(v.x); p.y = f2bf(v.y); p.z = f2bf(v.z); p.w = f2bf(v.w);
        *(ushort4*)(feat16 + (size_t)i * 4) = p;
        if (i < E) atomicAdd(&hist[dst[i] >> 8], 1);
        if (i < N) rmap[i] = root_idx[batch[i]];
        if (i < 128 * 128) {
            int k = i >> 7, c = i & 127;
            wt1[c * 128 + k] = f2bf(W1[i]);
        }
        if (i < 256 * 128) {
            int k = i >> 7, c = i & 127;
            wt2[c * 256 + k] = f2bf(W2[i]);
            wtl[c * 256 + k] = f2bf(Wl[i]);
        }
    }
    __syncthreads();
    if (threadIdx.x < nbuk) {
        int v = hist[threadIdx.x];
        if (v) atomicAdd(&bucket_count[threadIdx.x], v);
    }
}

__global__ void zero_small_kernel(int* __restrict__ p, int n) {
    int i = blockIdx.x * blockDim.x + threadIdx.x;
    if (i < n) p[i] = 0;
}

// A2: scan bucket counts -> bucket_base/cursor; rowstart[N]=E
__global__ __launch_bounds__(256) void scanA_kernel(const int* __restrict__ bucket_count,
                                                    int* __restrict__ bucket_base,
                                                    int* __restrict__ bucket_cursor,
                                                    int* __restrict__ rowstart,
                                                    int N, int E, int nbuk) {
    __shared__ int sb[256];
    const int t = threadIdx.x;
    int v = (t < nbuk) ? bucket_count[t] : 0;
    sb[t] = v;
    __syncthreads();
    for (int off = 1; off < 256; off <<= 1) {
        int x = (t >= off) ? sb[t - off] : 0;
        __syncthreads();
        sb[t] += x;
        __syncthreads();
    }
    if (t < nbuk) {
        int ex = sb[t] - v;
        bucket_base[t] = ex;
        bucket_cursor[t] = ex;
    }
    if (t == 0) {
        bucket_base[nbuk] = sb[255];
        rowstart[N] = E;
    }
}

// A3: bin edges into coarse-bucket segments of bstage, LDS-staged burst writes.
// Record: {src | (dst&255)<<16, val-bits}  (valid since N <= 65536)
__global__ __launch_bounds__(256) void binA_kernel(const int* __restrict__ src,
                                                   const int* __restrict__ dst,
                                                   const float* __restrict__ vals,
                                                   int* __restrict__ bucket_cursor,
                                                   int2* __restrict__ bstage,
                                                   int E, int nbuk) {
    __shared__ int hist[NBUK_MAX];
    __shared__ int lbase[NBUK_MAX + 1];
    __shared__ int gbase[NBUK_MAX];
    __shared__ int cur[NBUK_MAX];
    __shared__ int scanbuf[256];
    __shared__ int2 stage[ATILE];
    const int tid = threadIdx.x;
    const int t0 = blockIdx.x * ATILE;
    const int cnt = min(ATILE, E - t0);

    if (tid < nbuk) hist[tid] = 0;
    __syncthreads();

    int s8[8], d8[8], v8[8];
#pragma unroll
    for (int k = 0; k < 8; ++k) {
        const int li = k * 256 + tid;
        const bool ok = li < cnt;
        const int idx = t0 + li;
        s8[k] = ok ? src[idx] : 0;
        d8[k] = ok ? dst[idx] : 0;
        v8[k] = ok ? ((const int*)vals)[idx] : 0;
        if (ok) atomicAdd(&hist[d8[k] >> 8], 1);
    }
    __syncthreads();
    // exclusive scan of hist
    const int h = (tid < nbuk) ? hist[tid] : 0;
    scanbuf[tid] = h;
    __syncthreads();
    for (int off = 1; off < 256; off <<= 1) {
        int x = (tid >= off) ? scanbuf[tid - off] : 0;
        __syncthreads();
        scanbuf[tid] += x;
        __syncthreads();
    }
    if (tid < nbuk) {
        const int ex = scanbuf[tid] - h;
        lbase[tid] = ex;
        cur[tid] = ex;
        gbase[tid] = h ? atomicAdd(&bucket_cursor[tid], h) : 0;
    }
    if (tid == 0) lbase[nbuk] = cnt;
    __syncthreads();
    // LDS re-binning
#pragma unroll
    for (int k = 0; k < 8; ++k) {
        if ((k * 256 + tid) < cnt) {
            const int b = d8[k] >> 8;
            const int lp = atomicAdd(&cur[b], 1);
            stage[lp] = make_int2((s8[k] & 0xffff) | ((d8[k] & 255) << 16), v8[k]);
        }
    }
    __syncthreads();
    // burst copy-out (binary search for bucket of slot i)
    for (int i = tid; i < cnt; i += 256) {
        int lo = 0, hi = nbuk;
        while (hi - lo > 1) {
            const int mid = (lo + hi) >> 1;
            if (lbase[mid] <= i) lo = mid; else hi = mid;
        }
        bstage[gbase[lo] + (i - lbase[lo])] = stage[i];
    }
}

// B: per-bucket CSR finalize — per-node degrees, rowstart, and L2-local scatter.
__global__ __launch_bounds__(256) void binB_kernel(const int2* __restrict__ bstage,
                                                   const int* __restrict__ bucket_base,
                                                   int* __restrict__ rowstart,
                                                   int2* __restrict__ edata, int N) {
    __shared__ int deg_l[256];
    __shared__ int pfx[256];
    const int b = blockIdx.x;
    const int base = bucket_base[b], end = bucket_base[b + 1];
    const int n0 = b << 8;
    const int tid = threadIdx.x;
    deg_l[tid] = 0;
    __syncthreads();
    for (int i = base + tid; i < end; i += 256)
        atomicAdd(&deg_l[(bstage[i].x >> 16) & 255], 1);
    __syncthreads();
    const int v = deg_l[tid];
    pfx[tid] = v;
    __syncthreads();
    for (int off = 1; off < 256; off <<= 1) {
        int x = (tid >= off) ? pfx[tid - off] : 0;
        __syncthreads();
        pfx[tid] += x;
        __syncthreads();
    }
    const int ex = pfx[tid] - v;
    if (n0 + tid < N) rowstart[n0 + tid] = base + ex;
    __syncthreads();
    deg_l[tid] = ex;  // reuse as relative cursor
    __syncthreads();
    for (int i = base + tid; i < end; i += 256) {
        const int2 r = bstage[i];
        const int lp = atomicAdd(&deg_l[(r.x >> 16) & 255], 1);
        edata[base + lp] = make_int2(r.x & 0xffff, r.y);
    }
}

// h[i] = bf16( bias + sum_{e in CSR[i]} val_e * xw[src_e] )
// One node per 16-lane quarter-wave, 8-deep unroll -> up to 32 row loads
// in flight per wave. Per-column accumulation order is ascending-e (bitwise
// identical to previous rounds).
__global__ __launch_bounds__(256) void gather_kernel(const unsigned short* __restrict__ xw,
                                                     const int* __restrict__ rowstart,
                                                     const int2* __restrict__ edata,
                                                     const float* __restrict__ bias,
                                                     unsigned short* __restrict__ h, int N) {
    const int node = blockIdx.x * 16 + (threadIdx.x >> 4);
    const int ql = threadIdx.x & 15;        // lane within quarter: 8 bf16 columns
    if (node >= N) return;
    const int s0 = rowstart[node], s1 = rowstart[node + 1];
    const int c0 = ql * 8;
    float acc[8];
    {
        float4 b0 = *(const float4*)(bias + c0);
        float4 b1 = *(const float4*)(bias + c0 + 4);
        acc[0] = b0.x; acc[1] = b0.y; acc[2] = b0.z; acc[3] = b0.w;
        acc[4] = b1.x; acc[5] = b1.y; acc[6] = b1.z; acc[7] = b1.w;
    }
    int e = s0;
    for (; e + 8 <= s1; e += 8) {
        int2 ed[8];
#pragma unroll
        for (int j = 0; j < 8; ++j) ed[j] = edata[e + j];
        uint4 x[8];
#pragma unroll
        for (int j = 0; j < 8; ++j)
            x[j] = *(const uint4*)(xw + (size_t)ed[j].x * 128 + c0);
#pragma unroll
        for (int j = 0; j < 8; ++j) {
            const float v = __builtin_bit_cast(float, ed[j].y);
            const unsigned* p = &x[j].x;
#pragma unroll
            for (int q = 0; q < 4; ++q) {
                acc[2 * q]     = fmaf(v, bflo(p[q]), acc[2 * q]);
                acc[2 * q + 1] = fmaf(v, bfhi(p[q]), acc[2 * q + 1]);
            }
        }
    }
    for (; e < s1; ++e) {
        int2 e0 = edata[e];
        float v0 = __builtin_bit_cast(float, e0.y);
        uint4 x0 = *(const uint4*)(xw + (size_t)e0.x * 128 + c0);
        const unsigned* p0 = &x0.x;
#pragma unroll
        for (int q = 0; q < 4; ++q) {
            acc[2 * q]     = fmaf(v0, bflo(p0[q]), acc[2 * q]);
            acc[2 * q + 1] = fmaf(v0, bfhi(p0[q]), acc[2 * q + 1]);
        }
    }
    uint4 o;
    o.x = (unsigned)f2bf(acc[0]) | ((unsigned)f2bf(acc[1]) << 16);
    o.y = (unsigned)f2bf(acc[2]) | ((unsigned)f2bf(acc[3]) << 16);
    o.z = (unsigned)f2bf(acc[4]) | ((unsigned)f2bf(acc[5]) << 16);
    o.w = (unsigned)f2bf(acc[6]) | ((unsigned)f2bf(acc[7]) << 16);
    *(uint4*)(h + (size_t)node * 128 + c0) = o;
}

// MFMA GEMM v3: out[N,128] = act( concat(actA(A), actB(B2[rmap])) @ W (+bias) )
// - Full Wt resident in LDS (XOR-swizzled, loaded once, ONE barrier total)
// - ALL A fragments loaded upfront into a static-indexed register array
//   (loads fully overlap; no per-chunk exposed latency)
// - 128 rows/block, 8 waves (512 thr), barrier-free K loop
template <int K, bool LRA, bool LRB, bool LROUT, bool HASB, bool OUTBF>
__global__ __launch_bounds__(512) void mgemm_kernel(const unsigned short* __restrict__ A,
                                                    const unsigned short* __restrict__ B2,
                                                    const int* __restrict__ rmap,
                                                    const unsigned short* __restrict__ Wt,
                                                    const float* __restrict__ bias,
                                                    void* __restrict__ outv, int N) {
    __shared__ short Bs[128 * K];  // [col][k] bf16, k XOR-swizzled by ((col&7)<<3)
    const int tid = threadIdx.x;
    const int wv = tid >> 6, lane = tid & 63;
    const int lr = lane & 15, lg = lane >> 4;
    const int row0 = blockIdx.x * 128;

    // ---- stage ALL of Wt once: 4 threads/col, K/4 shorts each ----
    {
        const int col = tid >> 2, part = tid & 3;
        const int swz = (col & 7) << 3;
#pragma unroll
        for (int i = 0; i < K / 32; ++i) {
            const int k = part * (K / 4) + i * 8;
            short8 v = *(const short8*)(Wt + (size_t)col * K + k);
            *(short8*)&Bs[col * K + (k ^ swz)] = v;
        }
    }
    __syncthreads();  // the only barrier

    const int row = row0 + wv * 16 + lr;
    const int gr = row < N ? row : N - 1;
    const int rr = (K > 128) ? rmap[gr] : 0;
    const unsigned short* aptr = A + (size_t)gr * 128;
    const unsigned short* bptr = (K > 128) ? B2 + (size_t)rr * 128 : nullptr;

    f32x4 acc[8];
#pragma unroll
    for (int t = 0; t < 8; ++t) acc[t] = (f32x4){0.f, 0.f, 0.f, 0.f};

    // ---- load ALL A fragments upfront (static indices; 4*K/32 VGPRs) ----
    short8 raws[K / 32];
#pragma unroll
    for (int kc = 0; kc < K / 32; ++kc) {
        const int kbase = kc * 32 + lg * 8;
        if (K == 128 || kbase < 128)
            raws[kc] = *(const short8*)(aptr + kbase);
        else
            raws[kc] = *(const short8*)(bptr + (kbase - 128));
    }

#pragma unroll
    for (int kc = 0; kc < K / 32; ++kc) {
        short8 af = raws[kc];
        const bool dolr = (K == 128 || kc * 32 < 128) ? LRA : LRB;
        if (dolr) {
#pragma unroll
            for (int j = 0; j < 8; ++j)
                af[j] = (short)f2bf(lrelu(bf2f((unsigned short)af[j])));
        }
        const int kb = kc * 32 + lg * 8;
#pragma unroll
        for (int t = 0; t < 8; ++t) {
            const int col = t * 16 + lr;
            short8 bf = *(short8*)&Bs[col * K + (kb ^ ((col & 7) << 3))];
            acc[t] = __builtin_amdgcn_mfma_f32_16x16x32_bf16(af, bf, acc[t], 0, 0, 0);
        }
    }

    // ---- epilogue: C/D layout col=lane&15, row=(lane>>4)*4+reg ----
#pragma unroll
    for (int t = 0; t < 8; ++t) {
#pragma unroll
        for (int r = 0; r < 4; ++r) {
            int grr = row0 + wv * 16 + lg * 4 + r;
            if (grr < N) {
                float v = acc[t][r];
                if (HASB) v += bias[t * 16 + lr];
                if (LROUT) v = lrelu(v);
                if (OUTBF)
                    ((unsigned short*)outv)[(size_t)grr * 128 + t * 16 + lr] = f2bf(v);
                else
                    ((float*)outv)[(size_t)grr * 128 + t * 16 + lr] = v;
            }
        }
    }
}

extern "C" void kernel_launch(void* const* d_in, const int* in_sizes, int n_in,
                              void* d_out, int out_size, void* d_ws, size_t ws_size,
                              hipStream_t stream) {
    const float* features = (const float*)d_in[0];
    const float* values   = (const float*)d_in[1];
    const float* W1 = (const float*)d_in[2];
    const float* b1 = (const float*)d_in[3];
    const float* W2 = (const float*)d_in[4];
    const float* b2 = (const float*)d_in[5];
    const float* Wl = (const float*)d_in[6];
    const float* bl = (const float*)d_in[7];
    const int* adjs     = (const int*)d_in[8];
    const int* root_idx = (const int*)d_in[9];
    const int* batch    = (const int*)d_in[12];
    float* out = (float*)d_out;

    const int N = in_sizes[0] / 128;   // 50000 (< 65536: packed-record assumption)
    const int E = in_sizes[1];
    const int* src = adjs;
    const int* dst = adjs + E;
    const int nbuk = (N + 255) >> 8;   // 196

    const size_t nf = (size_t)N * 128;
    unsigned short* bufA   = (unsigned short*)d_ws;  // xw1/xw2 bf16 [N*128]
    unsigned short* h1     = bufA + nf;              // conv1 out bf16 (raw, +b1)
    unsigned short* h2     = h1 + nf;                // conv2 out bf16 (pre-lrelu, +b2)
    unsigned short* feat16 = h2 + nf;                // bf16 features
    unsigned short* wt1 = feat16 + nf;               // [128][128]
    unsigned short* wt2 = wt1 + 128 * 128;           // [128][256]
    unsigned short* wtl = wt2 + 256 * 128;           // [128][256]
    uintptr_t ep = ((uintptr_t)(wtl + 256 * 128) + 7) & ~(uintptr_t)7;
    int2* edata  = (int2*)ep;                        // final CSR records [E]
    int2* bstage = edata + E;                        // coarse-binned staging [E]
    int*  rmap     = (int*)(bstage + E);
    int*  rowstart = rmap + N;                       // [N+1]
    int*  bucket_count  = rowstart + N + 1;          // [nbuk]
    int*  bucket_base   = bucket_count + NBUK_MAX;   // [nbuk+1]
    int*  bucket_cursor = bucket_base + NBUK_MAX + 1;// [nbuk]

    const int gblocks = (N + 127) / 128;

    // ---- prep (+ fused dst histogram) + CSR build ----
    zero_small_kernel<<<1, 256, 0, stream>>>(bucket_count, NBUK_MAX);
    prep_kernel<<<1024, 256, 0, stream>>>(features, batch, root_idx, W1, W2, Wl,
                                          dst, feat16, rmap, bucket_count,
                                          wt1, wt2, wtl, N, E, nbuk);
    scanA_kernel<<<1, 256, 0, stream>>>(bucket_count, bucket_base, bucket_cursor,
                                        rowstart, N, E, nbuk);
    binA_kernel<<<(E + ATILE - 1) / ATILE, 256, 0, stream>>>(src, dst, values,
                                                             bucket_cursor, bstage, E, nbuk);
    binB_kernel<<<nbuk, 256, 0, stream>>>(bstage, bucket_base, rowstart, edata, N);

    // ---- conv1: xw1 = feat16 @ W1 ; h1 = bf16(b1 + gather) ----
    mgemm_kernel<128, false, false, false, false, true>
        <<<gblocks, 512, 0, stream>>>(feat16, nullptr, nullptr, wt1, nullptr, bufA, N);
    gather_kernel<<<(N + 15) / 16, 256, 0, stream>>>(bufA, rowstart, edata, b1, h1, N);

    // ---- conv2: xw2 = concat(lrelu(h1), lrelu(feat16[root])) @ W2 ; h2 = bf16(b2 + gather) ----
    mgemm_kernel<256, true, true, false, false, true>
        <<<gblocks, 512, 0, stream>>>(h1, feat16, rmap, wt2, nullptr, bufA, N);
    gather_kernel<<<(N + 15) / 16, 256, 0, stream>>>(bufA, rowstart, edata, b2, h2, N);

    // ---- out = lrelu( concat(lrelu(h2), h1[root]) @ Wl + bl )  (f32 out) ----
    mgemm_kernel<256, true, false, true, true, false>
        <<<gblocks, 512, 0, stream>>>(h2, h1, rmap, wtl, bl, out, N);
}

// Round 13
// 254.160 us; speedup vs baseline: 1.0765x; 1.0765x over previous
//
#include <hip/hip_runtime.h>
#include <hip/hip_bf16.h>

#define NEG_SLOPE 0.01f
#define NBUK_MAX 256
#define ATILE 2048

typedef __attribute__((ext_vector_type(8))) short short8;
typedef __attribute__((ext_vector_type(4))) float f32x4;

__device__ __forceinline__ float lrelu(float x) { return x > 0.f ? x : NEG_SLOPE * x; }

// f32 -> bf16 bits, round-to-nearest-even
__device__ __forceinline__ unsigned short f2bf(float f) {
    unsigned u = __builtin_bit_cast(unsigned, f);
    u += 0x7fffu + ((u >> 16) & 1u);
    return (unsigned short)(u >> 16);
}
__device__ __forceinline__ float bf2f(unsigned short h) {
    return __builtin_bit_cast(float, (unsigned)h << 16);
}
__device__ __forceinline__ float bflo(unsigned u) {
    return __builtin_bit_cast(float, u << 16);
}
__device__ __forceinline__ float bfhi(unsigned u) {
    return __builtin_bit_cast(float, u & 0xffff0000u);
}

// Fused prep: feat16 = bf16(features); rmap; bucket_count=0; transposed bf16 weights.
// (r12 lesson: do NOT fold the dst histogram in here — it regressed.)
__global__ __launch_bounds__(256) void prep_kernel(
        const float* __restrict__ features, const int* __restrict__ batch,
        const int* __restrict__ root_idx, const float* __restrict__ W1,
        const float* __restrict__ W2, const float* __restrict__ Wl,
        unsigned short* __restrict__ feat16, int* __restrict__ rmap,
        int* __restrict__ bucket_count, unsigned short* __restrict__ wt1,
        unsigned short* __restrict__ wt2, unsigned short* __restrict__ wtl,
        int N, int nbuk) {
    const int total = N * 32;  // float4 groups of features
    for (int i = blockIdx.x * blockDim.x + threadIdx.x; i < total;
         i += gridDim.x * blockDim.x) {
        float4 v = *(const float4*)(features + (size_t)i * 4);
        ushort4 p;
        p.x = f2bf(v.x); p.y = f2bf(v.y); p.z = f2bf(v.z); p.w = f2bf(v.w);
        *(ushort4*)(feat16 + (size_t)i * 4) = p;
        if (i < N) rmap[i] = root_idx[batch[i]];
        if (i < nbuk) bucket_count[i] = 0;
        if (i < 128 * 128) {
            int k = i >> 7, c = i & 127;
            wt1[c * 128 + k] = f2bf(W1[i]);
        }
        if (i < 256 * 128) {
            int k = i >> 7, c = i & 127;
            wt2[c * 256 + k] = f2bf(W2[i]);
            wtl[c * 256 + k] = f2bf(Wl[i]);
        }
    }
}

// A1: coarse histogram of dst>>8 (LDS-aggregated)
__global__ __launch_bounds__(256) void histA_kernel(const int* __restrict__ dst,
                                                    int* __restrict__ bucket_count,
                                                    int E, int nbuk) {
    __shared__ int hist[NBUK_MAX];
    if (threadIdx.x < nbuk) hist[threadIdx.x] = 0;
    __syncthreads();
    for (int e = blockIdx.x * blockDim.x + threadIdx.x; e < E; e += gridDim.x * blockDim.x)
        atomicAdd(&hist[dst[e] >> 8], 1);
    __syncthreads();
    if (threadIdx.x < nbuk) {
        int v = hist[threadIdx.x];
        if (v) atomicAdd(&bucket_count[threadIdx.x], v);
    }
}

// A2: scan bucket counts -> bucket_base/cursor; rowstart[N]=E
__global__ __launch_bounds__(256) void scanA_kernel(const int* __restrict__ bucket_count,
                                                    int* __restrict__ bucket_base,
                                                    int* __restrict__ bucket_cursor,
                                                    int* __restrict__ rowstart,
                                                    int N, int E, int nbuk) {
    __shared__ int sb[256];
    const int t = threadIdx.x;
    int v = (t < nbuk) ? bucket_count[t] : 0;
    sb[t] = v;
    __syncthreads();
    for (int off = 1; off < 256; off <<= 1) {
        int x = (t >= off) ? sb[t - off] : 0;
        __syncthreads();
        sb[t] += x;
        __syncthreads();
    }
    if (t < nbuk) {
        int ex = sb[t] - v;
        bucket_base[t] = ex;
        bucket_cursor[t] = ex;
    }
    if (t == 0) {
        bucket_base[nbuk] = sb[255];
        rowstart[N] = E;
    }
}

// A3: bin edges into coarse-bucket segments of bstage, LDS-staged burst writes.
// Record: {src | (dst&255)<<16, val-bits}  (valid since N <= 65536)
__global__ __launch_bounds__(256) void binA_kernel(const int* __restrict__ src,
                                                   const int* __restrict__ dst,
                                                   const float* __restrict__ vals,
                                                   int* __restrict__ bucket_cursor,
                                                   int2* __restrict__ bstage,
                                                   int E, int nbuk) {
    __shared__ int hist[NBUK_MAX];
    __shared__ int lbase[NBUK_MAX + 1];
    __shared__ int gbase[NBUK_MAX];
    __shared__ int cur[NBUK_MAX];
    __shared__ int scanbuf[256];
    __shared__ int2 stage[ATILE];
    const int tid = threadIdx.x;
    const int t0 = blockIdx.x * ATILE;
    const int cnt = min(ATILE, E - t0);

    if (tid < nbuk) hist[tid] = 0;
    __syncthreads();

    int s8[8], d8[8], v8[8];
#pragma unroll
    for (int k = 0; k < 8; ++k) {
        const int li = k * 256 + tid;
        const bool ok = li < cnt;
        const int idx = t0 + li;
        s8[k] = ok ? src[idx] : 0;
        d8[k] = ok ? dst[idx] : 0;
        v8[k] = ok ? ((const int*)vals)[idx] : 0;
        if (ok) atomicAdd(&hist[d8[k] >> 8], 1);
    }
    __syncthreads();
    // exclusive scan of hist
    const int h = (tid < nbuk) ? hist[tid] : 0;
    scanbuf[tid] = h;
    __syncthreads();
    for (int off = 1; off < 256; off <<= 1) {
        int x = (tid >= off) ? scanbuf[tid - off] : 0;
        __syncthreads();
        scanbuf[tid] += x;
        __syncthreads();
    }
    if (tid < nbuk) {
        const int ex = scanbuf[tid] - h;
        lbase[tid] = ex;
        cur[tid] = ex;
        gbase[tid] = h ? atomicAdd(&bucket_cursor[tid], h) : 0;
    }
    if (tid == 0) lbase[nbuk] = cnt;
    __syncthreads();
    // LDS re-binning
#pragma unroll
    for (int k = 0; k < 8; ++k) {
        if ((k * 256 + tid) < cnt) {
            const int b = d8[k] >> 8;
            const int lp = atomicAdd(&cur[b], 1);
            stage[lp] = make_int2((s8[k] & 0xffff) | ((d8[k] & 255) << 16), v8[k]);
        }
    }
    __syncthreads();
    // burst copy-out (binary search for bucket of slot i)
    for (int i = tid; i < cnt; i += 256) {
        int lo = 0, hi = nbuk;
        while (hi - lo > 1) {
            const int mid = (lo + hi) >> 1;
            if (lbase[mid] <= i) lo = mid; else hi = mid;
        }
        bstage[gbase[lo] + (i - lbase[lo])] = stage[i];
    }
}

// B: per-bucket CSR finalize — per-node degrees, rowstart, and L2-local scatter.
__global__ __launch_bounds__(256) void binB_kernel(const int2* __restrict__ bstage,
                                                   const int* __restrict__ bucket_base,
                                                   int* __restrict__ rowstart,
                                                   int2* __restrict__ edata, int N) {
    __shared__ int deg_l[256];
    __shared__ int pfx[256];
    const int b = blockIdx.x;
    const int base = bucket_base[b], end = bucket_base[b + 1];
    const int n0 = b << 8;
    const int tid = threadIdx.x;
    deg_l[tid] = 0;
    __syncthreads();
    for (int i = base + tid; i < end; i += 256)
        atomicAdd(&deg_l[(bstage[i].x >> 16) & 255], 1);
    __syncthreads();
    const int v = deg_l[tid];
    pfx[tid] = v;
    __syncthreads();
    for (int off = 1; off < 256; off <<= 1) {
        int x = (tid >= off) ? pfx[tid - off] : 0;
        __syncthreads();
        pfx[tid] += x;
        __syncthreads();
    }
    const int ex = pfx[tid] - v;
    if (n0 + tid < N) rowstart[n0 + tid] = base + ex;
    __syncthreads();
    deg_l[tid] = ex;  // reuse as relative cursor
    __syncthreads();
    for (int i = base + tid; i < end; i += 256) {
        const int2 r = bstage[i];
        const int lp = atomicAdd(&deg_l[(r.x >> 16) & 255], 1);
        edata[base + lp] = make_int2(r.x & 0xffff, r.y);
    }
}

// h[i] = bf16( bias + sum_{e in CSR[i]} val_e * xw[src_e] )
// One node per 16-lane quarter-wave: each lane loads 16 B (8 bf16) per edge,
// 4 independent edge streams per wave, unroll 4 -> up to 16 row loads in flight.
// (r12 lesson: unroll 8 regressed — occupancy loss beats extra MLP.)
__global__ __launch_bounds__(256) void gather_kernel(const unsigned short* __restrict__ xw,
                                                     const int* __restrict__ rowstart,
                                                     const int2* __restrict__ edata,
                                                     const float* __restrict__ bias,
                                                     unsigned short* __restrict__ h, int N) {
    const int node = blockIdx.x * 16 + (threadIdx.x >> 4);
    const int ql = threadIdx.x & 15;        // lane within quarter: 8 bf16 columns
    if (node >= N) return;
    const int s0 = rowstart[node], s1 = rowstart[node + 1];
    const int c0 = ql * 8;
    float acc[8];
    {
        float4 b0 = *(const float4*)(bias + c0);
        float4 b1 = *(const float4*)(bias + c0 + 4);
        acc[0] = b0.x; acc[1] = b0.y; acc[2] = b0.z; acc[3] = b0.w;
        acc[4] = b1.x; acc[5] = b1.y; acc[6] = b1.z; acc[7] = b1.w;
    }
    int e = s0;
    for (; e + 4 <= s1; e += 4) {
        int2 e0 = edata[e], e1 = edata[e + 1], e2 = edata[e + 2], e3 = edata[e + 3];
        uint4 x0 = *(const uint4*)(xw + (size_t)e0.x * 128 + c0);
        uint4 x1 = *(const uint4*)(xw + (size_t)e1.x * 128 + c0);
        uint4 x2 = *(const uint4*)(xw + (size_t)e2.x * 128 + c0);
        uint4 x3 = *(const uint4*)(xw + (size_t)e3.x * 128 + c0);
        float v0 = __builtin_bit_cast(float, e0.y), v1 = __builtin_bit_cast(float, e1.y);
        float v2 = __builtin_bit_cast(float, e2.y), v3 = __builtin_bit_cast(float, e3.y);
        const unsigned* p0 = &x0.x; const unsigned* p1 = &x1.x;
        const unsigned* p2 = &x2.x; const unsigned* p3 = &x3.x;
#pragma unroll
        for (int j = 0; j < 4; ++j) {
            acc[2 * j]     = fmaf(v0, bflo(p0[j]), acc[2 * j]);
            acc[2 * j + 1] = fmaf(v0, bfhi(p0[j]), acc[2 * j + 1]);
            acc[2 * j]     = fmaf(v1, bflo(p1[j]), acc[2 * j]);
            acc[2 * j + 1] = fmaf(v1, bfhi(p1[j]), acc[2 * j + 1]);
            acc[2 * j]     = fmaf(v2, bflo(p2[j]), acc[2 * j]);
            acc[2 * j + 1] = fmaf(v2, bfhi(p2[j]), acc[2 * j + 1]);
            acc[2 * j]     = fmaf(v3, bflo(p3[j]), acc[2 * j]);
            acc[2 * j + 1] = fmaf(v3, bfhi(p3[j]), acc[2 * j + 1]);
        }
    }
    for (; e < s1; ++e) {
        int2 e0 = edata[e];
        float v0 = __builtin_bit_cast(float, e0.y);
        uint4 x0 = *(const uint4*)(xw + (size_t)e0.x * 128 + c0);
        const unsigned* p0 = &x0.x;
#pragma unroll
        for (int j = 0; j < 4; ++j) {
            acc[2 * j]     = fmaf(v0, bflo(p0[j]), acc[2 * j]);
            acc[2 * j + 1] = fmaf(v0, bfhi(p0[j]), acc[2 * j + 1]);
        }
    }
    uint4 o;
    o.x = (unsigned)f2bf(acc[0]) | ((unsigned)f2bf(acc[1]) << 16);
    o.y = (unsigned)f2bf(acc[2]) | ((unsigned)f2bf(acc[3]) << 16);
    o.z = (unsigned)f2bf(acc[4]) | ((unsigned)f2bf(acc[5]) << 16);
    o.w = (unsigned)f2bf(acc[6]) | ((unsigned)f2bf(acc[7]) << 16);
    *(uint4*)(h + (size_t)node * 128 + c0) = o;
}

// MFMA GEMM v2: out[N,128] = act( concat(actA(A), actB(B2[rmap])) @ W (+bias) )
// - Full Wt resident in LDS (XOR-swizzled, loaded once, ONE barrier total)
// - A fragments loaded direct global->reg (no LDS), 1-deep prefetch
//   (r12 lesson: all-upfront register array regressed — keep 1-deep.)
// - 128 rows/block, 8 waves (512 thr), barrier-free K loop
template <int K, bool LRA, bool LRB, bool LROUT, bool HASB, bool OUTBF>
__global__ __launch_bounds__(512) void mgemm_kernel(const unsigned short* __restrict__ A,
                                                    const unsigned short* __restrict__ B2,
                                                    const int* __restrict__ rmap,
                                                    const unsigned short* __restrict__ Wt,
                                                    const float* __restrict__ bias,
                                                    void* __restrict__ outv, int N) {
    __shared__ short Bs[128 * K];  // [col][k] bf16, k XOR-swizzled by ((col&7)<<3)
    const int tid = threadIdx.x;
    const int wv = tid >> 6, lane = tid & 63;
    const int lr = lane & 15, lg = lane >> 4;
    const int row0 = blockIdx.x * 128;

    // ---- stage ALL of Wt once: 4 threads/col, K/4 shorts each ----
    {
        const int col = tid >> 2, part = tid & 3;
        const int swz = (col & 7) << 3;
#pragma unroll
        for (int i = 0; i < K / 32; ++i) {
            const int k = part * (K / 4) + i * 8;
            short8 v = *(const short8*)(Wt + (size_t)col * K + k);
            *(short8*)&Bs[col * K + (k ^ swz)] = v;
        }
    }
    __syncthreads();  // the only barrier

    const int row = row0 + wv * 16 + lr;
    const int gr = row < N ? row : N - 1;
    const int rr = (K > 128) ? rmap[gr] : 0;
    const unsigned short* aptr = A + (size_t)gr * 128;
    const unsigned short* bptr = (K > 128) ? B2 + (size_t)rr * 128 : nullptr;

    f32x4 acc[8];
#pragma unroll
    for (int t = 0; t < 8; ++t) acc[t] = (f32x4){0.f, 0.f, 0.f, 0.f};

    // raw fragment load for chunk kc (uniform A/B2 switch: boundary 128 is a
    // multiple of 32, so each chunk lies entirely on one side)
    auto loadraw = [&](int kc) -> short8 {
        const int kbase = kc * 32 + lg * 8;
        if (K == 128 || kbase < 128) return *(const short8*)(aptr + kbase);
        return *(const short8*)(bptr + (kbase - 128));
    };
    auto xform = [&](short8 v, int kc) -> short8 {
        const bool dolr = (K == 128 || kc * 32 < 128) ? LRA : LRB;
        if (dolr) {
#pragma unroll
            for (int j = 0; j < 8; ++j)
                v[j] = (short)f2bf(lrelu(bf2f((unsigned short)v[j])));
        }
        return v;
    };

    short8 raw = loadraw(0);
#pragma unroll 1   // keep live ranges short (round-1 spill lesson); 1-deep prefetch inside
    for (int kc = 0; kc < K / 32; ++kc) {
        short8 raw_nxt = (kc + 1 < K / 32) ? loadraw(kc + 1) : raw;  // issue early
        short8 af = xform(raw, kc);
        const int kb = kc * 32 + lg * 8;
#pragma unroll
        for (int t = 0; t < 8; ++t) {
            const int col = t * 16 + lr;
            short8 bf = *(short8*)&Bs[col * K + (kb ^ ((col & 7) << 3))];
            acc[t] = __builtin_amdgcn_mfma_f32_16x16x32_bf16(af, bf, acc[t], 0, 0, 0);
        }
        raw = raw_nxt;
    }

    // ---- epilogue: C/D layout col=lane&15, row=(lane>>4)*4+reg ----
#pragma unroll
    for (int t = 0; t < 8; ++t) {
#pragma unroll
        for (int r = 0; r < 4; ++r) {
            int grr = row0 + wv * 16 + lg * 4 + r;
            if (grr < N) {
                float v = acc[t][r];
                if (HASB) v += bias[t * 16 + lr];
                if (LROUT) v = lrelu(v);
                if (OUTBF)
                    ((unsigned short*)outv)[(size_t)grr * 128 + t * 16 + lr] = f2bf(v);
                else
                    ((float*)outv)[(size_t)grr * 128 + t * 16 + lr] = v;
            }
        }
    }
}

extern "C" void kernel_launch(void* const* d_in, const int* in_sizes, int n_in,
                              void* d_out, int out_size, void* d_ws, size_t ws_size,
                              hipStream_t stream) {
    const float* features = (const float*)d_in[0];
    const float* values   = (const float*)d_in[1];
    const float* W1 = (const float*)d_in[2];
    const float* b1 = (const float*)d_in[3];
    const float* W2 = (const float*)d_in[4];
    const float* b2 = (const float*)d_in[5];
    const float* Wl = (const float*)d_in[6];
    const float* bl = (const float*)d_in[7];
    const int* adjs     = (const int*)d_in[8];
    const int* root_idx = (const int*)d_in[9];
    const int* batch    = (const int*)d_in[12];
    float* out = (float*)d_out;

    const int N = in_sizes[0] / 128;   // 50000 (< 65536: packed-record assumption)
    const int E = in_sizes[1];
    const int* src = adjs;
    const int* dst = adjs + E;
    const int nbuk = (N + 255) >> 8;   // 196

    const size_t nf = (size_t)N * 128;
    unsigned short* bufA   = (unsigned short*)d_ws;  // xw1/xw2 bf16 [N*128]
    unsigned short* h1     = bufA + nf;              // conv1 out bf16 (raw, +b1)
    unsigned short* h2     = h1 + nf;                // conv2 out bf16 (pre-lrelu, +b2)
    unsigned short* feat16 = h2 + nf;                // bf16 features
    unsigned short* wt1 = feat16 + nf;               // [128][128]
    unsigned short* wt2 = wt1 + 128 * 128;           // [128][256]
    unsigned short* wtl = wt2 + 256 * 128;           // [128][256]
    uintptr_t ep = ((uintptr_t)(wtl + 256 * 128) + 7) & ~(uintptr_t)7;
    int2* edata  = (int2*)ep;                        // final CSR records [E]
    int2* bstage = edata + E;                        // coarse-binned staging [E]
    int*  rmap     = (int*)(bstage + E);
    int*  rowstart = rmap + N;                       // [N+1]
    int*  bucket_count  = rowstart + N + 1;          // [nbuk]
    int*  bucket_base   = bucket_count + NBUK_MAX;   // [nbuk+1]
    int*  bucket_cursor = bucket_base + NBUK_MAX + 1;// [nbuk]

    const int gblocks = (N + 127) / 128;

    // ---- prep + two-level CSR build ----
    prep_kernel<<<1024, 256, 0, stream>>>(features, batch, root_idx, W1, W2, Wl,
                                          feat16, rmap, bucket_count, wt1, wt2, wtl,
                                          N, nbuk);
    histA_kernel<<<256, 256, 0, stream>>>(dst, bucket_count, E, nbuk);
    scanA_kernel<<<1, 256, 0, stream>>>(bucket_count, bucket_base, bucket_cursor,
                                        rowstart, N, E, nbuk);
    binA_kernel<<<(E + ATILE - 1) / ATILE, 256, 0, stream>>>(src, dst, values,
                                                             bucket_cursor, bstage, E, nbuk);
    binB_kernel<<<nbuk, 256, 0, stream>>>(bstage, bucket_base, rowstart, edata, N);

    // ---- conv1: xw1 = feat16 @ W1 ; h1 = bf16(b1 + gather) ----
    mgemm_kernel<128, false, false, false, false, true>
        <<<gblocks, 512, 0, stream>>>(feat16, nullptr, nullptr, wt1, nullptr, bufA, N);
    gather_kernel<<<(N + 15) / 16, 256, 0, stream>>>(bufA, rowstart, edata, b1, h1, N);

    // ---- conv2: xw2 = concat(lrelu(h1), lrelu(feat16[root])) @ W2 ; h2 = bf16(b2 + gather) ----
    mgemm_kernel<256, true, true, false, false, true>
        <<<gblocks, 512, 0, stream>>>(h1, feat16, rmap, wt2, nullptr, bufA, N);
    gather_kernel<<<(N + 15) / 16, 256, 0, stream>>>(bufA, rowstart, edata, b2, h2, N);

    // ---- out = lrelu( concat(lrelu(h2), h1[root]) @ Wl + bl )  (f32 out) ----
    mgemm_kernel<256, true, false, true, true, false>
        <<<gblocks, 512, 0, stream>>>(h2, h1, rmap, wtl, bl, out, N);
}